// Round 4
// baseline (1517.120 us; speedup 1.0000x reference)
//
#include <hip/hip_runtime.h>

#define NG 8192
#define LN_EPS 1e-5f

typedef float v2f __attribute__((ext_vector_type(2)));

// ---------------- DPP wave-scan helpers (VALU-only, no LDS pipe) ----------------

__device__ __forceinline__ float wscan_add(float x) {
  x += __int_as_float(__builtin_amdgcn_update_dpp(0, __float_as_int(x), 0x111, 0xF, 0xF, true));
  x += __int_as_float(__builtin_amdgcn_update_dpp(0, __float_as_int(x), 0x112, 0xF, 0xF, true));
  x += __int_as_float(__builtin_amdgcn_update_dpp(0, __float_as_int(x), 0x114, 0xF, 0xF, true));
  x += __int_as_float(__builtin_amdgcn_update_dpp(0, __float_as_int(x), 0x118, 0xF, 0xF, true));
  x += __int_as_float(__builtin_amdgcn_update_dpp(0, __float_as_int(x), 0x142, 0xA, 0xF, false));
  x += __int_as_float(__builtin_amdgcn_update_dpp(0, __float_as_int(x), 0x143, 0xC, 0xF, false));
  return x;
}

__device__ __forceinline__ int wscan_max(int x) {
  int t;
  t = __builtin_amdgcn_update_dpp(0, x, 0x111, 0xF, 0xF, true); x = max(x, t);
  t = __builtin_amdgcn_update_dpp(0, x, 0x112, 0xF, 0xF, true); x = max(x, t);
  t = __builtin_amdgcn_update_dpp(0, x, 0x114, 0xF, 0xF, true); x = max(x, t);
  t = __builtin_amdgcn_update_dpp(0, x, 0x118, 0xF, 0xF, true); x = max(x, t);
  t = __builtin_amdgcn_update_dpp(0, x, 0x142, 0xA, 0xF, false); x = max(x, t);
  t = __builtin_amdgcn_update_dpp(0, x, 0x143, 0xC, 0xF, false); x = max(x, t);
  return x;
}

// ---------------- misc helpers ----------------

__device__ __forceinline__ void stage4(float* dst, const float* __restrict__ src,
                                       int n4, int tid, int nt) {
  float4* d = (float4*)dst;
  const float4* s = (const float4*)src;
  for (int t = tid; t < n4; t += nt) d[t] = s[t];
}

__device__ __forceinline__ void load20v(const float* __restrict__ p, v2f v[10]) {
  const float4* q = (const float4*)p;
#pragma unroll
  for (int t = 0; t < 5; t++) {
    float4 f = q[t];
    v[2*t]   = (v2f){f.x, f.y};
    v[2*t+1] = (v2f){f.z, f.w};
  }
}

__device__ __forceinline__ void store20v(float* __restrict__ p, const v2f v[10]) {
  float4* q = (float4*)p;
#pragma unroll
  for (int t = 0; t < 5; t++)
    q[t] = make_float4(v[2*t].x, v[2*t].y, v[2*t+1].x, v[2*t+1].y);
}

__device__ __forceinline__ float elem(const v2f* a, int k) { return a[k >> 1][k & 1]; }

// LN(relu(relu(h1)@W2+b2)@W3+b3)*g+be — packed fp32 pairs. Works for both
// global (SGPR s_load) and LDS (broadcast ds_read) weight pointers (inlined).
__device__ __forceinline__ void mlp23_ln1(
    const float* __restrict__ W2, const float* __restrict__ b2,
    const float* __restrict__ W3, const float* __restrict__ b3,
    const float* __restrict__ g,  const float* __restrict__ be,
    const v2f h1[10], v2f out[10]) {
  const v2f* W2v = (const v2f*)W2; const v2f* b2v = (const v2f*)b2;
  const v2f* W3v = (const v2f*)W3; const v2f* b3v = (const v2f*)b3;
  const v2f* gv  = (const v2f*)g;  const v2f* bev = (const v2f*)be;
  v2f h2[10];
#pragma unroll
  for (int j = 0; j < 10; j++) h2[j] = b2v[j];
#pragma unroll
  for (int k = 0; k < 20; k++) {
    float a = fmaxf(elem(h1, k), 0.0f); v2f av = {a, a};
#pragma unroll
    for (int j = 0; j < 10; j++) h2[j] += av * W2v[k*10 + j];
  }
  v2f h3[10];
#pragma unroll
  for (int j = 0; j < 10; j++) h3[j] = b3v[j];
#pragma unroll
  for (int k = 0; k < 20; k++) {
    float a = fmaxf(elem(h2, k), 0.0f); v2f av = {a, a};
#pragma unroll
    for (int j = 0; j < 10; j++) h3[j] += av * W3v[k*10 + j];
  }
  float mu = 0.0f;
#pragma unroll
  for (int j = 0; j < 10; j++) mu += h3[j].x + h3[j].y;
  mu *= 0.05f;
  float var = 0.0f;
#pragma unroll
  for (int j = 0; j < 10; j++) {
    float dx = h3[j].x - mu, dy = h3[j].y - mu;
    var += dx*dx + dy*dy;
  }
  var *= 0.05f;
  float rs = rsqrtf(var + LN_EPS);
  v2f muv = {mu, mu}, rsv = {rs, rs};
#pragma unroll
  for (int j = 0; j < 10; j++) out[j] = (h3[j] - muv) * rsv * gv[j] + bev[j];
}

// ---------------- kernels ----------------

__global__ __launch_bounds__(256) void k_prelayer(
    float* __restrict__ u, float* __restrict__ part, float* __restrict__ gu,
    const float* __restrict__ nmb1, const float* __restrict__ gpb1) {
  int t = blockIdx.x * 256 + threadIdx.x;   // NG*80 threads
  part[t] = 0.0f;
  if (t < NG * 40) {
    int j = t % 40;
    gu[t] = (j < 20) ? nmb1[j] : gpb1[j - 20];
  }
  if (t < NG * 20) u[t] = 0.0f;
}

__global__ __launch_bounds__(256) void k_init(
    const float* __restrict__ xin, float* __restrict__ xs,
    const float* __restrict__ W1, const float* __restrict__ b1,
    const float* __restrict__ W2, const float* __restrict__ b2,
    const float* __restrict__ W3, const float* __restrict__ b3,
    const float* __restrict__ gw, const float* __restrict__ bw, int n) {
  int i = blockIdx.x * 256 + threadIdx.x;
  if (i >= n) return;
  float xi[10];
  const float2* xp = (const float2*)(xin + (size_t)i * 10);
#pragma unroll
  for (int t = 0; t < 5; t++) { float2 f = xp[t]; xi[t*2] = f.x; xi[t*2+1] = f.y; }
  const v2f* W1v = (const v2f*)W1; const v2f* b1v = (const v2f*)b1;
  v2f h1[10];
#pragma unroll
  for (int j = 0; j < 10; j++) h1[j] = b1v[j];
#pragma unroll
  for (int k = 0; k < 10; k++) {
    float a = xi[k]; v2f av = {a, a};
#pragma unroll
    for (int j = 0; j < 10; j++) h1[j] += av * W1v[k*10 + j];
  }
  v2f out[10];
  mlp23_ln1(W2, b2, W3, b3, gw, bw, h1, out);
  store20v(xs + (size_t)i * 20, out);
}

// Per-layer node kernel, 1 node/thread, pk-fp32. ALL weights (NodeModel +
// pre-aggr) staged per-block into LDS and read as broadcast ds_read_b128
// (conflict-free). Rationale (round 3 post-mortem): SGPR=112 from s_load
// weight-streaming capped residency at 7 blocks/CU -> 1954-block grid ran a
// second ~27us straggler generation at 0.6 blocks/CU; forcing (256,8) with
// the SMEM stream still present caused scratch spills (+21MB HBM). Moving
// weights to LDS removes the SGPR pressure so 8 blocks/CU is reachable
// WITHOUT spills -> single-generation execution.
// Aggregation: deterministic DPP scan + run-end slot STORES (no atomics ->
// bitwise replay-stable).
__global__ __launch_bounds__(256, 8) void k_node(
    const int* __restrict__ batch, float* __restrict__ xs,
    const float* __restrict__ gu, float* __restrict__ part,
    const float* __restrict__ nmW1, const float* __restrict__ nmW2,
    const float* __restrict__ nmW3, const float* __restrict__ nmb2,
    const float* __restrict__ nmb3, const float* __restrict__ nmg,
    const float* __restrict__ nmbe,
    const float* __restrict__ gpW1, const float* __restrict__ gpW2,
    const float* __restrict__ gpW3, const float* __restrict__ gpb2,
    const float* __restrict__ gpb3, const float* __restrict__ gpg,
    const float* __restrict__ gpbe, int n) {
  __shared__ float sm[2560];
  int tid = threadIdx.x;
  // nm blob at 0, gp blob at 1280: [W1 400][W2 400][W3 400][b2 20][b3 20][g 20][be 20]
  stage4(sm + 0,    nmW1, 100, tid, 256);
  stage4(sm + 400,  nmW2, 100, tid, 256);
  stage4(sm + 800,  nmW3, 100, tid, 256);
  stage4(sm + 1200, nmb2, 5,   tid, 256);
  stage4(sm + 1220, nmb3, 5,   tid, 256);
  stage4(sm + 1240, nmg,  5,   tid, 256);
  stage4(sm + 1260, nmbe, 5,   tid, 256);
  stage4(sm + 1280, gpW1, 100, tid, 256);
  stage4(sm + 1680, gpW2, 100, tid, 256);
  stage4(sm + 2080, gpW3, 100, tid, 256);
  stage4(sm + 2480, gpb2, 5,   tid, 256);
  stage4(sm + 2500, gpb3, 5,   tid, 256);
  stage4(sm + 2520, gpg,  5,   tid, 256);
  stage4(sm + 2540, gpbe, 5,   tid, 256);
  __syncthreads();

  int i = blockIdx.x * 256 + tid;
  int lane = tid & 63;
  bool valid = i < n;
  int ic = valid ? i : (n - 1);
  int b = batch[ic];

  v2f x[10];
  load20v(xs + (size_t)ic * 20, x);

  // ---- NodeModel: h1 = x@W1x + gu_nm[b]  (gu = u@W1u + b1, prefolded) ----
  v2f h1[10];
  load20v(gu + (size_t)b * 40, h1);
  const v2f* W1v = (const v2f*)sm;
#pragma unroll
  for (int k = 0; k < 20; k++) {
    float a = elem(x, k); v2f av = {a, a};
#pragma unroll
    for (int j = 0; j < 10; j++) h1[j] += av * W1v[k*10 + j];
  }
  v2f xn[10];
  mlp23_ln1(sm + 400, sm + 1200, sm + 800, sm + 1220, sm + 1240, sm + 1260,
            h1, xn);
#pragma unroll
  for (int j = 0; j < 10; j++) xn[j] += x[j];     // residual
  if (valid) store20v(xs + (size_t)ic * 20, xn);

  // ---- pre-aggr MLP on updated x (weights from LDS broadcast) ----
  v2f p1[10];
  load20v(gu + (size_t)b * 40 + 20, p1);
  const v2f* G1v = (const v2f*)(sm + 1280);
#pragma unroll
  for (int k = 0; k < 20; k++) {
    float a = elem(xn, k); v2f av = {a, a};
#pragma unroll
    for (int j = 0; j < 10; j++) p1[j] += av * G1v[k*10 + j];
  }
  v2f pre[10];
  mlp23_ln1(sm + 1680, sm + 2480, sm + 2080, sm + 2500, sm + 2520, sm + 2540,
            p1, pre);

  // ---- aggregation: DPP scan + run-end slot stores (batch sorted) ----
  int key = valid ? b : -1;
  if (!valid) {
#pragma unroll
    for (int j = 0; j < 10; j++) pre[j] = (v2f){0.0f, 0.0f};
  }
  int pk = __builtin_amdgcn_update_dpp(-1, key, 0x138, 0xF, 0xF, false);
  int nk = __builtin_amdgcn_update_dpp(-2, key, 0x130, 0xF, 0xF, false);
  bool isstart = (key != pk);
  int st = wscan_max(isstart ? lane : 0);   // start lane of my run

#pragma unroll
  for (int j = 0; j < 10; j++) {
    pre[j].x = wscan_add(pre[j].x);
    pre[j].y = wscan_add(pre[j].y);
  }

  int pl = (st > 0) ? (st - 1) : 0;
  float use = (st > 0) ? 1.0f : 0.0f;
  v2f fl[10];
#pragma unroll
  for (int j = 0; j < 10; j++) {
    float bx = __shfl(pre[j].x, pl);
    float by = __shfl(pre[j].y, pl);
    fl[j].x = pre[j].x - use * bx;
    fl[j].y = pre[j].y - use * by;
  }
  bool runend = valid && (nk != key);       // lane63 gets nk=-2 -> true
  if (runend) {
    int slot = (i >> 6) & 3;                // graphs span <=4 consecutive waves
    float* pp = part + (size_t)b * 80 + slot * 20;
#pragma unroll
    for (int j = 0; j < 10; j++) {
      pp[2*j]     = fl[j].x;
      pp[2*j + 1] = fl[j].y;
    }
  }
}

// Per-layer global kernel, 4 LANES PER GRAPH (NG*4 threads): coalesced slot
// loads, fixed-tree shfl butterflies, transposed weights in LDS. No slot
// re-zero needed — batch is constant across layers, so exactly the same
// (graph, slot) pairs are rewritten every layer; slots never written stay
// at their k_prelayer zeros.
__global__ __launch_bounds__(128) void k_global(
    float* __restrict__ u, float* __restrict__ part, float* __restrict__ gu,
    const float* __restrict__ qW1, const float* __restrict__ qb1,
    const float* __restrict__ qW2, const float* __restrict__ qb2,
    const float* __restrict__ qW3, const float* __restrict__ qb3,
    const float* __restrict__ qg,  const float* __restrict__ qbe,
    const float* __restrict__ nmW1u, const float* __restrict__ nmb1n,
    const float* __restrict__ gpW1u, const float* __restrict__ gpb1n,
    int has_next) {
  __shared__ float sW1T[20 * 40];   // [j][k], k over (agg | u)
  __shared__ float sW2T[20 * 20];   // [j][k]
  __shared__ float sW3T[20 * 20];
  __shared__ float sNT[20 * 20];    // nmW1u^T (next layer)
  __shared__ float sGT[20 * 20];    // gpW1u^T (next layer)
  __shared__ float sB[140];         // qb1|qb2|qb3|qg|qbe|nmb1n|gpb1n
  int tid = threadIdx.x;
  for (int e = tid; e < 800; e += 128) sW1T[(e % 20) * 40 + (e / 20)] = qW1[e];
  for (int e = tid; e < 400; e += 128) {
    int k = e / 20, j = e % 20;
    sW2T[j * 20 + k] = qW2[e];
    sW3T[j * 20 + k] = qW3[e];
    sNT[j * 20 + k]  = nmW1u[e];
    sGT[j * 20 + k]  = gpW1u[e];
  }
  if (tid < 20) {
    sB[tid]       = qb1[tid];
    sB[20 + tid]  = qb2[tid];
    sB[40 + tid]  = qb3[tid];
    sB[60 + tid]  = qg[tid];
    sB[80 + tid]  = qbe[tid];
    sB[100 + tid] = nmb1n[tid];
    sB[120 + tid] = gpb1n[tid];
  }
  __syncthreads();

  int t = blockIdx.x * 128 + tid;   // exactly NG*4 threads
  int g = t >> 2;                   // graph
  int q = t & 3;                    // quarter: output cols [q*5, q*5+5)
  int lane = tid & 63;
  int gl = lane & ~3;               // group base lane (groups never cross waves)

  // my partial slot (coalesced 80B/lane), then fixed-tree butterfly sum
  float a[20];
  {
    const float4* p = (const float4*)(part + (size_t)g * 80 + q * 20);
#pragma unroll
    for (int i = 0; i < 5; i++) {
      float4 f = p[i];
      a[4*i] = f.x; a[4*i+1] = f.y; a[4*i+2] = f.z; a[4*i+3] = f.w;
    }
  }
#pragma unroll
  for (int i = 0; i < 20; i++) {
    a[i] += __shfl_xor(a[i], 1);
    a[i] += __shfl_xor(a[i], 2);    // (s0+s1)+(s2+s3), same on all 4 lanes
  }

  float uu[20];
  {
    const float4* p = (const float4*)(u + (size_t)g * 20);
#pragma unroll
    for (int i = 0; i < 5; i++) {
      float4 f = p[i];
      uu[4*i] = f.x; uu[4*i+1] = f.y; uu[4*i+2] = f.z; uu[4*i+3] = f.w;
    }
  }

  // h1 slice: j = q*5+o ; h1_j = qb1[j] + a.W1[:,j](rows 0..19) + uu.W1[:,j](rows 20..39)
  float h1[5];
#pragma unroll
  for (int o = 0; o < 5; o++) {
    int j = q * 5 + o;
    const v2f* w = (const v2f*)(sW1T + j * 40);
    v2f acc = {0.0f, 0.0f};
#pragma unroll
    for (int kk = 0; kk < 10; kk++) acc += (v2f){a[2*kk], a[2*kk+1]} * w[kk];
#pragma unroll
    for (int kk = 0; kk < 10; kk++) acc += (v2f){uu[2*kk], uu[2*kk+1]} * w[10 + kk];
    h1[o] = sB[j] + acc.x + acc.y;
  }

  // gather relu(h1) across the 4-lane group (static unroll -> static reg idx)
  float r1[20];
#pragma unroll
  for (int k = 0; k < 20; k++)
    r1[k] = fmaxf(__shfl(h1[k % 5], gl + (k / 5)), 0.0f);

  float h2[5];
#pragma unroll
  for (int o = 0; o < 5; o++) {
    int j = q * 5 + o;
    const v2f* w = (const v2f*)(sW2T + j * 20);
    v2f acc = {0.0f, 0.0f};
#pragma unroll
    for (int kk = 0; kk < 10; kk++) acc += (v2f){r1[2*kk], r1[2*kk+1]} * w[kk];
    h2[o] = sB[20 + j] + acc.x + acc.y;
  }

  float r2[20];
#pragma unroll
  for (int k = 0; k < 20; k++)
    r2[k] = fmaxf(__shfl(h2[k % 5], gl + (k / 5)), 0.0f);

  float h3[5];
#pragma unroll
  for (int o = 0; o < 5; o++) {
    int j = q * 5 + o;
    const v2f* w = (const v2f*)(sW3T + j * 20);
    v2f acc = {0.0f, 0.0f};
#pragma unroll
    for (int kk = 0; kk < 10; kk++) acc += (v2f){r2[2*kk], r2[2*kk+1]} * w[kk];
    h3[o] = sB[40 + j] + acc.x + acc.y;
  }

  // group LayerNorm (fixed-tree butterflies)
  float s = h3[0] + h3[1] + h3[2] + h3[3] + h3[4];
  s += __shfl_xor(s, 1);
  s += __shfl_xor(s, 2);
  float mu = s * 0.05f;
  float d = 0.0f;
#pragma unroll
  for (int o = 0; o < 5; o++) { float dd = h3[o] - mu; d += dd * dd; }
  d += __shfl_xor(d, 1);
  d += __shfl_xor(d, 2);
  float rs = rsqrtf(d * 0.05f + LN_EPS);

  float un[5];
#pragma unroll
  for (int o = 0; o < 5; o++) {
    int j = q * 5 + o;
    un[o] = (h3[o] - mu) * rs * sB[60 + j] + sB[80 + j] + uu[j];  // +residual
  }
#pragma unroll
  for (int o = 0; o < 5; o++) u[(size_t)g * 20 + q * 5 + o] = un[o];

  if (has_next) {
    float ru[20];
#pragma unroll
    for (int k = 0; k < 20; k++)
      ru[k] = __shfl(un[k % 5], gl + (k / 5));
    float gn[5], gg[5];
#pragma unroll
    for (int o = 0; o < 5; o++) {
      int j = q * 5 + o;
      const v2f* wn = (const v2f*)(sNT + j * 20);
      const v2f* wg = (const v2f*)(sGT + j * 20);
      v2f an = {0.0f, 0.0f}, ag = {0.0f, 0.0f};
#pragma unroll
      for (int kk = 0; kk < 10; kk++) {
        v2f rv = {ru[2*kk], ru[2*kk+1]};
        an += rv * wn[kk];
        ag += rv * wg[kk];
      }
      gn[o] = sB[100 + j] + an.x + an.y;
      gg[o] = sB[120 + j] + ag.x + ag.y;
    }
#pragma unroll
    for (int o = 0; o < 5; o++) {
      gu[(size_t)g * 40 + q * 5 + o]      = gn[o];
      gu[(size_t)g * 40 + 20 + q * 5 + o] = gg[o];
    }
  }
}

// ---------------- host launcher ----------------

extern "C" void kernel_launch(void* const* d_in, const int* in_sizes, int n_in,
                              void* d_out, int out_size, void* d_ws, size_t ws_size,
                              hipStream_t stream) {
  const float* x_in  = (const float*)d_in[0];
  const int*   batch = (const int*)  d_in[1];
  const float* ni_W1 = (const float*)d_in[2];
  const float* ni_b1 = (const float*)d_in[3];
  const float* ni_W2 = (const float*)d_in[4];
  const float* ni_b2 = (const float*)d_in[5];
  const float* ni_W3 = (const float*)d_in[6];
  const float* ni_b3 = (const float*)d_in[7];
  const float* ni_g  = (const float*)d_in[8];
  const float* ni_be = (const float*)d_in[9];
  const float* nm_W1 = (const float*)d_in[10];
  const float* nm_b1 = (const float*)d_in[11];
  const float* nm_W2 = (const float*)d_in[12];
  const float* nm_b2 = (const float*)d_in[13];
  const float* nm_W3 = (const float*)d_in[14];
  const float* nm_b3 = (const float*)d_in[15];
  const float* nm_g  = (const float*)d_in[16];
  const float* nm_be = (const float*)d_in[17];
  const float* gp_W1 = (const float*)d_in[18];
  const float* gp_b1 = (const float*)d_in[19];
  const float* gp_W2 = (const float*)d_in[20];
  const float* gp_b2 = (const float*)d_in[21];
  const float* gp_W3 = (const float*)d_in[22];
  const float* gp_b3 = (const float*)d_in[23];
  const float* gp_g  = (const float*)d_in[24];
  const float* gp_be = (const float*)d_in[25];
  const float* gq_W1 = (const float*)d_in[26];
  const float* gq_b1 = (const float*)d_in[27];
  const float* gq_W2 = (const float*)d_in[28];
  const float* gq_b2 = (const float*)d_in[29];
  const float* gq_W3 = (const float*)d_in[30];
  const float* gq_b3 = (const float*)d_in[31];
  const float* gq_g  = (const float*)d_in[32];
  const float* gq_be = (const float*)d_in[33];

  const int N = in_sizes[0] / 10;          // 500000
  float* xs = (float*)d_out;               // x state in d_out[0 .. N*20)
  float* u  = xs + (size_t)N * 20;         // u in d_out tail (NG*20)

  float* part = (float*)d_ws;              // NG*80 (4 slots x 20 per graph)
  float* gu   = part + NG * 80;            // NG*40 (merged nm|gp table)

  const int L = 20;
  const int nblk = (N + 255) / 256;

  k_prelayer<<<(NG * 80) / 256, 256, 0, stream>>>(u, part, gu, nm_b1, gp_b1);
  k_init<<<nblk, 256, 0, stream>>>(x_in, xs, ni_W1, ni_b1, ni_W2, ni_b2,
                                   ni_W3, ni_b3, ni_g, ni_be, N);
  for (int l = 0; l < L; l++) {
    k_node<<<nblk, 256, 0, stream>>>(batch, xs, gu, part,
        nm_W1 + (size_t)l * 800, nm_W2 + (size_t)l * 400, nm_W3 + (size_t)l * 400,
        nm_b2 + l * 20, nm_b3 + l * 20, nm_g + l * 20, nm_be + l * 20,
        gp_W1 + (size_t)l * 800, gp_W2 + (size_t)l * 400, gp_W3 + (size_t)l * 400,
        gp_b2 + l * 20, gp_b3 + l * 20, gp_g + l * 20, gp_be + l * 20, N);
    int has_next = (l < L - 1);
    k_global<<<(NG * 4) / 128, 128, 0, stream>>>(u, part, gu,
        gq_W1 + (size_t)l * 800, gq_b1 + l * 20,
        gq_W2 + (size_t)l * 400, gq_b2 + l * 20,
        gq_W3 + (size_t)l * 400, gq_b3 + l * 20,
        gq_g + l * 20, gq_be + l * 20,
        nm_W1 + (size_t)(l + 1) * 800 + 400, nm_b1 + (l + 1) * 20,
        gp_W1 + (size_t)(l + 1) * 800 + 400, gp_b1 + (l + 1) * 20,
        has_next);
  }
}

// Round 5
// 1331.416 us; speedup vs baseline: 1.1395x; 1.1395x over previous
//
#include <hip/hip_runtime.h>

#define NG 8192
#define LN_EPS 1e-5f

typedef float v2f __attribute__((ext_vector_type(2)));

// ---------------- DPP wave-scan helpers (VALU-only, no LDS pipe) ----------------

__device__ __forceinline__ float wscan_add(float x) {
  x += __int_as_float(__builtin_amdgcn_update_dpp(0, __float_as_int(x), 0x111, 0xF, 0xF, true));
  x += __int_as_float(__builtin_amdgcn_update_dpp(0, __float_as_int(x), 0x112, 0xF, 0xF, true));
  x += __int_as_float(__builtin_amdgcn_update_dpp(0, __float_as_int(x), 0x114, 0xF, 0xF, true));
  x += __int_as_float(__builtin_amdgcn_update_dpp(0, __float_as_int(x), 0x118, 0xF, 0xF, true));
  x += __int_as_float(__builtin_amdgcn_update_dpp(0, __float_as_int(x), 0x142, 0xA, 0xF, false));
  x += __int_as_float(__builtin_amdgcn_update_dpp(0, __float_as_int(x), 0x143, 0xC, 0xF, false));
  return x;
}

__device__ __forceinline__ int wscan_max(int x) {
  int t;
  t = __builtin_amdgcn_update_dpp(0, x, 0x111, 0xF, 0xF, true); x = max(x, t);
  t = __builtin_amdgcn_update_dpp(0, x, 0x112, 0xF, 0xF, true); x = max(x, t);
  t = __builtin_amdgcn_update_dpp(0, x, 0x114, 0xF, 0xF, true); x = max(x, t);
  t = __builtin_amdgcn_update_dpp(0, x, 0x118, 0xF, 0xF, true); x = max(x, t);
  t = __builtin_amdgcn_update_dpp(0, x, 0x142, 0xA, 0xF, false); x = max(x, t);
  t = __builtin_amdgcn_update_dpp(0, x, 0x143, 0xC, 0xF, false); x = max(x, t);
  return x;
}

// ---------------- misc helpers ----------------

__device__ __forceinline__ void stage4(float* dst, const float* __restrict__ src,
                                       int n4, int tid, int nt) {
  float4* d = (float4*)dst;
  const float4* s = (const float4*)src;
  for (int t = tid; t < n4; t += nt) d[t] = s[t];
}

__device__ __forceinline__ void load20v(const float* __restrict__ p, v2f v[10]) {
  const float4* q = (const float4*)p;
#pragma unroll
  for (int t = 0; t < 5; t++) {
    float4 f = q[t];
    v[2*t]   = (v2f){f.x, f.y};
    v[2*t+1] = (v2f){f.z, f.w};
  }
}

__device__ __forceinline__ void store20v(float* __restrict__ p, const v2f v[10]) {
  float4* q = (float4*)p;
#pragma unroll
  for (int t = 0; t < 5; t++)
    q[t] = make_float4(v[2*t].x, v[2*t].y, v[2*t+1].x, v[2*t+1].y);
}

__device__ __forceinline__ float elem(const v2f* a, int k) { return a[k >> 1][k & 1]; }

// LN(relu(relu(h1)@W2+b2)@W3+b3)*g+be — packed fp32 pairs. Works for both
// global (SGPR s_load) and LDS (broadcast ds_read) weight pointers (inlined).
__device__ __forceinline__ void mlp23_ln1(
    const float* __restrict__ W2, const float* __restrict__ b2,
    const float* __restrict__ W3, const float* __restrict__ b3,
    const float* __restrict__ g,  const float* __restrict__ be,
    const v2f h1[10], v2f out[10]) {
  const v2f* W2v = (const v2f*)W2; const v2f* b2v = (const v2f*)b2;
  const v2f* W3v = (const v2f*)W3; const v2f* b3v = (const v2f*)b3;
  const v2f* gv  = (const v2f*)g;  const v2f* bev = (const v2f*)be;
  v2f h2[10];
#pragma unroll
  for (int j = 0; j < 10; j++) h2[j] = b2v[j];
#pragma unroll
  for (int k = 0; k < 20; k++) {
    float a = fmaxf(elem(h1, k), 0.0f); v2f av = {a, a};
#pragma unroll
    for (int j = 0; j < 10; j++) h2[j] += av * W2v[k*10 + j];
  }
  v2f h3[10];
#pragma unroll
  for (int j = 0; j < 10; j++) h3[j] = b3v[j];
#pragma unroll
  for (int k = 0; k < 20; k++) {
    float a = fmaxf(elem(h2, k), 0.0f); v2f av = {a, a};
#pragma unroll
    for (int j = 0; j < 10; j++) h3[j] += av * W3v[k*10 + j];
  }
  float mu = 0.0f;
#pragma unroll
  for (int j = 0; j < 10; j++) mu += h3[j].x + h3[j].y;
  mu *= 0.05f;
  float var = 0.0f;
#pragma unroll
  for (int j = 0; j < 10; j++) {
    float dx = h3[j].x - mu, dy = h3[j].y - mu;
    var += dx*dx + dy*dy;
  }
  var *= 0.05f;
  float rs = rsqrtf(var + LN_EPS);
  v2f muv = {mu, mu}, rsv = {rs, rs};
#pragma unroll
  for (int j = 0; j < 10; j++) out[j] = (h3[j] - muv) * rsv * gv[j] + bev[j];
}

// ---------------- kernels ----------------

__global__ __launch_bounds__(256) void k_prelayer(
    float* __restrict__ u, float* __restrict__ part, float* __restrict__ gu,
    const float* __restrict__ nmb1, const float* __restrict__ gpb1) {
  int t = blockIdx.x * 256 + threadIdx.x;   // NG*80 threads
  part[t] = 0.0f;
  if (t < NG * 40) {
    int j = t % 40;
    gu[t] = (j < 20) ? nmb1[j] : gpb1[j - 20];
  }
  if (t < NG * 20) u[t] = 0.0f;
}

// One-time weight packer: per layer l, blob of 2560 floats =
// [nmW1x 400][nmW2 400][nmW3 400][nmb2 20][nmb3 20][nmg 20][nmbe 20] (=1280)
// [gpW1x 400][gpW2 400][gpW3 400][gpb2 20][gpb3 20][gpg 20][gpbe 20] (=1280)
// Purpose: k_node then takes ONE weight pointer -> ~30 fewer live SGPRs of
// kernarg bases, dropping SGPR below 100 so 8 blocks/CU (capacity 2048 >=
// 1954-block grid) is reached with NATURAL codegen (round-3/4 showed that
// forcing launch_bounds crushes VGPR and spills to scratch).
__global__ __launch_bounds__(256) void k_pack(
    float* __restrict__ wp,
    const float* __restrict__ nmW1, const float* __restrict__ nmW2,
    const float* __restrict__ nmW3, const float* __restrict__ nmb2,
    const float* __restrict__ nmb3, const float* __restrict__ nmg,
    const float* __restrict__ nmbe,
    const float* __restrict__ gpW1, const float* __restrict__ gpW2,
    const float* __restrict__ gpW3, const float* __restrict__ gpb2,
    const float* __restrict__ gpb3, const float* __restrict__ gpg,
    const float* __restrict__ gpbe) {
  int t = blockIdx.x * 256 + threadIdx.x;
  if (t >= 20 * 2560) return;
  int l = t / 2560, r = t % 2560;
  int half = (r >= 1280) ? 1 : 0;
  int rr = r - half * 1280;
  float v;
  if (rr < 400)       v = (half ? gpW1 : nmW1)[l * 800 + rr];       // x-rows only
  else if (rr < 800)  v = (half ? gpW2 : nmW2)[l * 400 + rr - 400];
  else if (rr < 1200) v = (half ? gpW3 : nmW3)[l * 400 + rr - 800];
  else if (rr < 1220) v = (half ? gpb2 : nmb2)[l * 20 + rr - 1200];
  else if (rr < 1240) v = (half ? gpb3 : nmb3)[l * 20 + rr - 1220];
  else if (rr < 1260) v = (half ? gpg  : nmg )[l * 20 + rr - 1240];
  else                v = (half ? gpbe : nmbe)[l * 20 + rr - 1260];
  wp[t] = v;
}

__global__ __launch_bounds__(256) void k_init(
    const float* __restrict__ xin, float* __restrict__ xs,
    const float* __restrict__ W1, const float* __restrict__ b1,
    const float* __restrict__ W2, const float* __restrict__ b2,
    const float* __restrict__ W3, const float* __restrict__ b3,
    const float* __restrict__ gw, const float* __restrict__ bw, int n) {
  int i = blockIdx.x * 256 + threadIdx.x;
  if (i >= n) return;
  float xi[10];
  const float2* xp = (const float2*)(xin + (size_t)i * 10);
#pragma unroll
  for (int t = 0; t < 5; t++) { float2 f = xp[t]; xi[t*2] = f.x; xi[t*2+1] = f.y; }
  const v2f* W1v = (const v2f*)W1; const v2f* b1v = (const v2f*)b1;
  v2f h1[10];
#pragma unroll
  for (int j = 0; j < 10; j++) h1[j] = b1v[j];
#pragma unroll
  for (int k = 0; k < 10; k++) {
    float a = xi[k]; v2f av = {a, a};
#pragma unroll
    for (int j = 0; j < 10; j++) h1[j] += av * W1v[k*10 + j];
  }
  v2f out[10];
  mlp23_ln1(W2, b2, W3, b3, gw, bw, h1, out);
  store20v(xs + (size_t)i * 20, out);
}

// Per-layer node kernel, 1 node/thread, pk-fp32 — round-0 body (known-good
// codegen: VGPR~36, no spills) with the weight args collapsed to ONE packed
// pointer. NodeModel weights stream via s_load (SGPR operands, immediate
// offsets off a single base); pre-aggr blob staged per-block into LDS
// (one contiguous 1280-float copy) and read as broadcast ds_read_b128.
// Aggregation: deterministic DPP scan + run-end slot stores (no atomics).
__global__ __launch_bounds__(256) void k_node(
    const int* __restrict__ batch, float* __restrict__ xs,
    float* __restrict__ ws, const float* __restrict__ wl, int n) {
  float* part = ws;                         // NG*80
  const float* gu = ws + NG * 80;           // NG*40
  __shared__ float sm[1280];
  int tid = threadIdx.x;
  stage4(sm, wl + 1280, 320, tid, 256);     // whole gp blob, contiguous
  __syncthreads();

  int i = blockIdx.x * 256 + tid;
  int lane = tid & 63;
  bool valid = i < n;
  int ic = valid ? i : (n - 1);
  int b = batch[ic];

  v2f x[10];
  load20v(xs + (size_t)ic * 20, x);

  // ---- NodeModel: h1 = x@W1x + gu_nm[b]  (gu = u@W1u + b1, prefolded) ----
  v2f h1[10];
  load20v(gu + (size_t)b * 40, h1);
  const v2f* W1v = (const v2f*)wl;
#pragma unroll
  for (int k = 0; k < 20; k++) {
    float a = elem(x, k); v2f av = {a, a};
#pragma unroll
    for (int j = 0; j < 10; j++) h1[j] += av * W1v[k*10 + j];
  }
  v2f xn[10];
  mlp23_ln1(wl + 400, wl + 1200, wl + 800, wl + 1220, wl + 1240, wl + 1260,
            h1, xn);
#pragma unroll
  for (int j = 0; j < 10; j++) xn[j] += x[j];     // residual
  if (valid) store20v(xs + (size_t)ic * 20, xn);

  // ---- pre-aggr MLP on updated x (weights from LDS broadcast) ----
  v2f p1[10];
  load20v(gu + (size_t)b * 40 + 20, p1);
  const v2f* G1v = (const v2f*)sm;
#pragma unroll
  for (int k = 0; k < 20; k++) {
    float a = elem(xn, k); v2f av = {a, a};
#pragma unroll
    for (int j = 0; j < 10; j++) p1[j] += av * G1v[k*10 + j];
  }
  v2f pre[10];
  mlp23_ln1(sm + 400, sm + 1200, sm + 800, sm + 1220, sm + 1240, sm + 1260,
            p1, pre);

  // ---- aggregation: DPP scan + run-end slot stores (batch sorted) ----
  int key = valid ? b : -1;
  if (!valid) {
#pragma unroll
    for (int j = 0; j < 10; j++) pre[j] = (v2f){0.0f, 0.0f};
  }
  int pk = __builtin_amdgcn_update_dpp(-1, key, 0x138, 0xF, 0xF, false);
  int nk = __builtin_amdgcn_update_dpp(-2, key, 0x130, 0xF, 0xF, false);
  bool isstart = (key != pk);
  int st = wscan_max(isstart ? lane : 0);   // start lane of my run

#pragma unroll
  for (int j = 0; j < 10; j++) {
    pre[j].x = wscan_add(pre[j].x);
    pre[j].y = wscan_add(pre[j].y);
  }

  int pl = (st > 0) ? (st - 1) : 0;
  float use = (st > 0) ? 1.0f : 0.0f;
  v2f fl[10];
#pragma unroll
  for (int j = 0; j < 10; j++) {
    float bx = __shfl(pre[j].x, pl);
    float by = __shfl(pre[j].y, pl);
    fl[j].x = pre[j].x - use * bx;
    fl[j].y = pre[j].y - use * by;
  }
  bool runend = valid && (nk != key);       // lane63 gets nk=-2 -> true
  if (runend) {
    int slot = (i >> 6) & 3;                // graphs span <=4 consecutive waves
    float* pp = part + (size_t)b * 80 + slot * 20;
#pragma unroll
    for (int j = 0; j < 10; j++) {
      pp[2*j]     = fl[j].x;
      pp[2*j + 1] = fl[j].y;
    }
  }
}

// Per-layer global kernel, 4 LANES PER GRAPH (NG*4 threads): coalesced slot
// loads, fixed-tree shfl butterflies, transposed weights in LDS. No slot
// re-zero needed — batch is constant across layers, so exactly the same
// (graph, slot) pairs are rewritten every layer; slots never written stay
// at their k_prelayer zeros.
__global__ __launch_bounds__(128) void k_global(
    float* __restrict__ u, float* __restrict__ part, float* __restrict__ gu,
    const float* __restrict__ qW1, const float* __restrict__ qb1,
    const float* __restrict__ qW2, const float* __restrict__ qb2,
    const float* __restrict__ qW3, const float* __restrict__ qb3,
    const float* __restrict__ qg,  const float* __restrict__ qbe,
    const float* __restrict__ nmW1u, const float* __restrict__ nmb1n,
    const float* __restrict__ gpW1u, const float* __restrict__ gpb1n,
    int has_next) {
  __shared__ float sW1T[20 * 40];   // [j][k], k over (agg | u)
  __shared__ float sW2T[20 * 20];   // [j][k]
  __shared__ float sW3T[20 * 20];
  __shared__ float sNT[20 * 20];    // nmW1u^T (next layer)
  __shared__ float sGT[20 * 20];    // gpW1u^T (next layer)
  __shared__ float sB[140];         // qb1|qb2|qb3|qg|qbe|nmb1n|gpb1n
  int tid = threadIdx.x;
  for (int e = tid; e < 800; e += 128) sW1T[(e % 20) * 40 + (e / 20)] = qW1[e];
  for (int e = tid; e < 400; e += 128) {
    int k = e / 20, j = e % 20;
    sW2T[j * 20 + k] = qW2[e];
    sW3T[j * 20 + k] = qW3[e];
    sNT[j * 20 + k]  = nmW1u[e];
    sGT[j * 20 + k]  = gpW1u[e];
  }
  if (tid < 20) {
    sB[tid]       = qb1[tid];
    sB[20 + tid]  = qb2[tid];
    sB[40 + tid]  = qb3[tid];
    sB[60 + tid]  = qg[tid];
    sB[80 + tid]  = qbe[tid];
    sB[100 + tid] = nmb1n[tid];
    sB[120 + tid] = gpb1n[tid];
  }
  __syncthreads();

  int t = blockIdx.x * 128 + tid;   // exactly NG*4 threads
  int g = t >> 2;                   // graph
  int q = t & 3;                    // quarter: output cols [q*5, q*5+5)
  int lane = tid & 63;
  int gl = lane & ~3;               // group base lane (groups never cross waves)

  // my partial slot (coalesced 80B/lane), then fixed-tree butterfly sum
  float a[20];
  {
    const float4* p = (const float4*)(part + (size_t)g * 80 + q * 20);
#pragma unroll
    for (int i = 0; i < 5; i++) {
      float4 f = p[i];
      a[4*i] = f.x; a[4*i+1] = f.y; a[4*i+2] = f.z; a[4*i+3] = f.w;
    }
  }
#pragma unroll
  for (int i = 0; i < 20; i++) {
    a[i] += __shfl_xor(a[i], 1);
    a[i] += __shfl_xor(a[i], 2);    // (s0+s1)+(s2+s3), same on all 4 lanes
  }

  float uu[20];
  {
    const float4* p = (const float4*)(u + (size_t)g * 20);
#pragma unroll
    for (int i = 0; i < 5; i++) {
      float4 f = p[i];
      uu[4*i] = f.x; uu[4*i+1] = f.y; uu[4*i+2] = f.z; uu[4*i+3] = f.w;
    }
  }

  // h1 slice: j = q*5+o ; h1_j = qb1[j] + a.W1[:,j](rows 0..19) + uu.W1[:,j](rows 20..39)
  float h1[5];
#pragma unroll
  for (int o = 0; o < 5; o++) {
    int j = q * 5 + o;
    const v2f* w = (const v2f*)(sW1T + j * 40);
    v2f acc = {0.0f, 0.0f};
#pragma unroll
    for (int kk = 0; kk < 10; kk++) acc += (v2f){a[2*kk], a[2*kk+1]} * w[kk];
#pragma unroll
    for (int kk = 0; kk < 10; kk++) acc += (v2f){uu[2*kk], uu[2*kk+1]} * w[10 + kk];
    h1[o] = sB[j] + acc.x + acc.y;
  }

  // gather relu(h1) across the 4-lane group (static unroll -> static reg idx)
  float r1[20];
#pragma unroll
  for (int k = 0; k < 20; k++)
    r1[k] = fmaxf(__shfl(h1[k % 5], gl + (k / 5)), 0.0f);

  float h2[5];
#pragma unroll
  for (int o = 0; o < 5; o++) {
    int j = q * 5 + o;
    const v2f* w = (const v2f*)(sW2T + j * 20);
    v2f acc = {0.0f, 0.0f};
#pragma unroll
    for (int kk = 0; kk < 10; kk++) acc += (v2f){r1[2*kk], r1[2*kk+1]} * w[kk];
    h2[o] = sB[20 + j] + acc.x + acc.y;
  }

  float r2[20];
#pragma unroll
  for (int k = 0; k < 20; k++)
    r2[k] = fmaxf(__shfl(h2[k % 5], gl + (k / 5)), 0.0f);

  float h3[5];
#pragma unroll
  for (int o = 0; o < 5; o++) {
    int j = q * 5 + o;
    const v2f* w = (const v2f*)(sW3T + j * 20);
    v2f acc = {0.0f, 0.0f};
#pragma unroll
    for (int kk = 0; kk < 10; kk++) acc += (v2f){r2[2*kk], r2[2*kk+1]} * w[kk];
    h3[o] = sB[40 + j] + acc.x + acc.y;
  }

  // group LayerNorm (fixed-tree butterflies)
  float s = h3[0] + h3[1] + h3[2] + h3[3] + h3[4];
  s += __shfl_xor(s, 1);
  s += __shfl_xor(s, 2);
  float mu = s * 0.05f;
  float d = 0.0f;
#pragma unroll
  for (int o = 0; o < 5; o++) { float dd = h3[o] - mu; d += dd * dd; }
  d += __shfl_xor(d, 1);
  d += __shfl_xor(d, 2);
  float rs = rsqrtf(d * 0.05f + LN_EPS);

  float un[5];
#pragma unroll
  for (int o = 0; o < 5; o++) {
    int j = q * 5 + o;
    un[o] = (h3[o] - mu) * rs * sB[60 + j] + sB[80 + j] + uu[j];  // +residual
  }
#pragma unroll
  for (int o = 0; o < 5; o++) u[(size_t)g * 20 + q * 5 + o] = un[o];

  if (has_next) {
    float ru[20];
#pragma unroll
    for (int k = 0; k < 20; k++)
      ru[k] = __shfl(un[k % 5], gl + (k / 5));
    float gn[5], gg[5];
#pragma unroll
    for (int o = 0; o < 5; o++) {
      int j = q * 5 + o;
      const v2f* wn = (const v2f*)(sNT + j * 20);
      const v2f* wg = (const v2f*)(sGT + j * 20);
      v2f an = {0.0f, 0.0f}, ag = {0.0f, 0.0f};
#pragma unroll
      for (int kk = 0; kk < 10; kk++) {
        v2f rv = {ru[2*kk], ru[2*kk+1]};
        an += rv * wn[kk];
        ag += rv * wg[kk];
      }
      gn[o] = sB[100 + j] + an.x + an.y;
      gg[o] = sB[120 + j] + ag.x + ag.y;
    }
#pragma unroll
    for (int o = 0; o < 5; o++) {
      gu[(size_t)g * 40 + q * 5 + o]      = gn[o];
      gu[(size_t)g * 40 + 20 + q * 5 + o] = gg[o];
    }
  }
}

// ---------------- host launcher ----------------

extern "C" void kernel_launch(void* const* d_in, const int* in_sizes, int n_in,
                              void* d_out, int out_size, void* d_ws, size_t ws_size,
                              hipStream_t stream) {
  const float* x_in  = (const float*)d_in[0];
  const int*   batch = (const int*)  d_in[1];
  const float* ni_W1 = (const float*)d_in[2];
  const float* ni_b1 = (const float*)d_in[3];
  const float* ni_W2 = (const float*)d_in[4];
  const float* ni_b2 = (const float*)d_in[5];
  const float* ni_W3 = (const float*)d_in[6];
  const float* ni_b3 = (const float*)d_in[7];
  const float* ni_g  = (const float*)d_in[8];
  const float* ni_be = (const float*)d_in[9];
  const float* nm_W1 = (const float*)d_in[10];
  const float* nm_b1 = (const float*)d_in[11];
  const float* nm_W2 = (const float*)d_in[12];
  const float* nm_b2 = (const float*)d_in[13];
  const float* nm_W3 = (const float*)d_in[14];
  const float* nm_b3 = (const float*)d_in[15];
  const float* nm_g  = (const float*)d_in[16];
  const float* nm_be = (const float*)d_in[17];
  const float* gp_W1 = (const float*)d_in[18];
  const float* gp_b1 = (const float*)d_in[19];
  const float* gp_W2 = (const float*)d_in[20];
  const float* gp_b2 = (const float*)d_in[21];
  const float* gp_W3 = (const float*)d_in[22];
  const float* gp_b3 = (const float*)d_in[23];
  const float* gp_g  = (const float*)d_in[24];
  const float* gp_be = (const float*)d_in[25];
  const float* gq_W1 = (const float*)d_in[26];
  const float* gq_b1 = (const float*)d_in[27];
  const float* gq_W2 = (const float*)d_in[28];
  const float* gq_b2 = (const float*)d_in[29];
  const float* gq_W3 = (const float*)d_in[30];
  const float* gq_b3 = (const float*)d_in[31];
  const float* gq_g  = (const float*)d_in[32];
  const float* gq_be = (const float*)d_in[33];

  const int N = in_sizes[0] / 10;          // 500000
  float* xs = (float*)d_out;               // x state in d_out[0 .. N*20)
  float* u  = xs + (size_t)N * 20;         // u in d_out tail (NG*20)

  float* part  = (float*)d_ws;             // NG*80 (4 slots x 20 per graph)
  float* gu    = part + NG * 80;           // NG*40 (merged nm|gp table)
  float* wpack = gu + NG * 40;             // L*2560 packed k_node weights

  const int L = 20;
  const int nblk = (N + 255) / 256;

  k_prelayer<<<(NG * 80) / 256, 256, 0, stream>>>(u, part, gu, nm_b1, gp_b1);
  k_pack<<<(L * 2560 + 255) / 256, 256, 0, stream>>>(wpack,
      nm_W1, nm_W2, nm_W3, nm_b2, nm_b3, nm_g, nm_be,
      gp_W1, gp_W2, gp_W3, gp_b2, gp_b3, gp_g, gp_be);
  k_init<<<nblk, 256, 0, stream>>>(x_in, xs, ni_W1, ni_b1, ni_W2, ni_b2,
                                   ni_W3, ni_b3, ni_g, ni_be, N);
  for (int l = 0; l < L; l++) {
    k_node<<<nblk, 256, 0, stream>>>(batch, xs, (float*)d_ws,
                                     wpack + (size_t)l * 2560, N);
    int has_next = (l < L - 1);
    k_global<<<(NG * 4) / 128, 128, 0, stream>>>(u, part, gu,
        gq_W1 + (size_t)l * 800, gq_b1 + l * 20,
        gq_W2 + (size_t)l * 400, gq_b2 + l * 20,
        gq_W3 + (size_t)l * 400, gq_b3 + l * 20,
        gq_g + l * 20, gq_be + l * 20,
        nm_W1 + (size_t)(l + 1) * 800 + 400, nm_b1 + (l + 1) * 20,
        gp_W1 + (size_t)(l + 1) * 800 + 400, gp_b1 + (l + 1) * 20,
        has_next);
  }
}

// Round 6
// 1307.155 us; speedup vs baseline: 1.1606x; 1.0186x over previous
//
#include <hip/hip_runtime.h>

#define NG 8192
#define LN_EPS 1e-5f

typedef float v2f __attribute__((ext_vector_type(2)));

// ---------------- DPP wave-scan helpers (VALU-only, no LDS pipe) ----------------

__device__ __forceinline__ float wscan_add(float x) {
  x += __int_as_float(__builtin_amdgcn_update_dpp(0, __float_as_int(x), 0x111, 0xF, 0xF, true));
  x += __int_as_float(__builtin_amdgcn_update_dpp(0, __float_as_int(x), 0x112, 0xF, 0xF, true));
  x += __int_as_float(__builtin_amdgcn_update_dpp(0, __float_as_int(x), 0x114, 0xF, 0xF, true));
  x += __int_as_float(__builtin_amdgcn_update_dpp(0, __float_as_int(x), 0x118, 0xF, 0xF, true));
  x += __int_as_float(__builtin_amdgcn_update_dpp(0, __float_as_int(x), 0x142, 0xA, 0xF, false));
  x += __int_as_float(__builtin_amdgcn_update_dpp(0, __float_as_int(x), 0x143, 0xC, 0xF, false));
  return x;
}

__device__ __forceinline__ int wscan_max(int x) {
  int t;
  t = __builtin_amdgcn_update_dpp(0, x, 0x111, 0xF, 0xF, true); x = max(x, t);
  t = __builtin_amdgcn_update_dpp(0, x, 0x112, 0xF, 0xF, true); x = max(x, t);
  t = __builtin_amdgcn_update_dpp(0, x, 0x114, 0xF, 0xF, true); x = max(x, t);
  t = __builtin_amdgcn_update_dpp(0, x, 0x118, 0xF, 0xF, true); x = max(x, t);
  t = __builtin_amdgcn_update_dpp(0, x, 0x142, 0xA, 0xF, false); x = max(x, t);
  t = __builtin_amdgcn_update_dpp(0, x, 0x143, 0xC, 0xF, false); x = max(x, t);
  return x;
}

// ---------------- misc helpers ----------------

__device__ __forceinline__ void stage4(float* dst, const float* __restrict__ src,
                                       int n4, int tid, int nt) {
  float4* d = (float4*)dst;
  const float4* s = (const float4*)src;
  for (int t = tid; t < n4; t += nt) d[t] = s[t];
}

__device__ __forceinline__ void load20v(const float* __restrict__ p, v2f v[10]) {
  const float4* q = (const float4*)p;
#pragma unroll
  for (int t = 0; t < 5; t++) {
    float4 f = q[t];
    v[2*t]   = (v2f){f.x, f.y};
    v[2*t+1] = (v2f){f.z, f.w};
  }
}

__device__ __forceinline__ void store20v(float* __restrict__ p, const v2f v[10]) {
  float4* q = (float4*)p;
#pragma unroll
  for (int t = 0; t < 5; t++)
    q[t] = make_float4(v[2*t].x, v[2*t].y, v[2*t+1].x, v[2*t+1].y);
}

__device__ __forceinline__ float elem(const v2f* a, int k) { return a[k >> 1][k & 1]; }

// LN(relu(relu(h1)@W2+b2)@W3+b3)*g+be — packed fp32 pairs. Works for both
// global (SGPR s_load) and LDS (broadcast ds_read) weight pointers (inlined).
__device__ __forceinline__ void mlp23_ln1(
    const float* __restrict__ W2, const float* __restrict__ b2,
    const float* __restrict__ W3, const float* __restrict__ b3,
    const float* __restrict__ g,  const float* __restrict__ be,
    const v2f h1[10], v2f out[10]) {
  const v2f* W2v = (const v2f*)W2; const v2f* b2v = (const v2f*)b2;
  const v2f* W3v = (const v2f*)W3; const v2f* b3v = (const v2f*)b3;
  const v2f* gv  = (const v2f*)g;  const v2f* bev = (const v2f*)be;
  v2f h2[10];
#pragma unroll
  for (int j = 0; j < 10; j++) h2[j] = b2v[j];
#pragma unroll
  for (int k = 0; k < 20; k++) {
    float a = fmaxf(elem(h1, k), 0.0f); v2f av = {a, a};
#pragma unroll
    for (int j = 0; j < 10; j++) h2[j] += av * W2v[k*10 + j];
  }
  v2f h3[10];
#pragma unroll
  for (int j = 0; j < 10; j++) h3[j] = b3v[j];
#pragma unroll
  for (int k = 0; k < 20; k++) {
    float a = fmaxf(elem(h2, k), 0.0f); v2f av = {a, a};
#pragma unroll
    for (int j = 0; j < 10; j++) h3[j] += av * W3v[k*10 + j];
  }
  float mu = 0.0f;
#pragma unroll
  for (int j = 0; j < 10; j++) mu += h3[j].x + h3[j].y;
  mu *= 0.05f;
  float var = 0.0f;
#pragma unroll
  for (int j = 0; j < 10; j++) {
    float dx = h3[j].x - mu, dy = h3[j].y - mu;
    var += dx*dx + dy*dy;
  }
  var *= 0.05f;
  float rs = rsqrtf(var + LN_EPS);
  v2f muv = {mu, mu}, rsv = {rs, rs};
#pragma unroll
  for (int j = 0; j < 10; j++) out[j] = (h3[j] - muv) * rsv * gv[j] + bev[j];
}

// ---------------- kernels ----------------

__global__ __launch_bounds__(256) void k_prelayer(
    float* __restrict__ u, float* __restrict__ part, float* __restrict__ gu,
    const float* __restrict__ nmb1, const float* __restrict__ gpb1) {
  int t = blockIdx.x * 256 + threadIdx.x;   // NG*80 threads
  part[t] = 0.0f;
  if (t < NG * 40) {
    int j = t % 40;
    gu[t] = (j < 20) ? nmb1[j] : gpb1[j - 20];
  }
  if (t < NG * 20) u[t] = 0.0f;
}

// One-time weight packer: per layer l, blob of 2560 floats =
// [nmW1x 400][nmW2 400][nmW3 400][nmb2 20][nmb3 20][nmg 20][nmbe 20] (=1280)
// [gpW1x 400][gpW2 400][gpW3 400][gpb2 20][gpb3 20][gpg 20][gpbe 20] (=1280)
__global__ __launch_bounds__(256) void k_pack(
    float* __restrict__ wp,
    const float* __restrict__ nmW1, const float* __restrict__ nmW2,
    const float* __restrict__ nmW3, const float* __restrict__ nmb2,
    const float* __restrict__ nmb3, const float* __restrict__ nmg,
    const float* __restrict__ nmbe,
    const float* __restrict__ gpW1, const float* __restrict__ gpW2,
    const float* __restrict__ gpW3, const float* __restrict__ gpb2,
    const float* __restrict__ gpb3, const float* __restrict__ gpg,
    const float* __restrict__ gpbe) {
  int t = blockIdx.x * 256 + threadIdx.x;
  if (t >= 20 * 2560) return;
  int l = t / 2560, r = t % 2560;
  int half = (r >= 1280) ? 1 : 0;
  int rr = r - half * 1280;
  float v;
  if (rr < 400)       v = (half ? gpW1 : nmW1)[l * 800 + rr];       // x-rows only
  else if (rr < 800)  v = (half ? gpW2 : nmW2)[l * 400 + rr - 400];
  else if (rr < 1200) v = (half ? gpW3 : nmW3)[l * 400 + rr - 800];
  else if (rr < 1220) v = (half ? gpb2 : nmb2)[l * 20 + rr - 1200];
  else if (rr < 1240) v = (half ? gpb3 : nmb3)[l * 20 + rr - 1220];
  else if (rr < 1260) v = (half ? gpg  : nmg )[l * 20 + rr - 1240];
  else                v = (half ? gpbe : nmbe)[l * 20 + rr - 1260];
  wp[t] = v;
}

__global__ __launch_bounds__(256) void k_init(
    const float* __restrict__ xin, float* __restrict__ xs,
    const float* __restrict__ W1, const float* __restrict__ b1,
    const float* __restrict__ W2, const float* __restrict__ b2,
    const float* __restrict__ W3, const float* __restrict__ b3,
    const float* __restrict__ gw, const float* __restrict__ bw, int n) {
  int i = blockIdx.x * 256 + threadIdx.x;
  if (i >= n) return;
  float xi[10];
  const float2* xp = (const float2*)(xin + (size_t)i * 10);
#pragma unroll
  for (int t = 0; t < 5; t++) { float2 f = xp[t]; xi[t*2] = f.x; xi[t*2+1] = f.y; }
  const v2f* W1v = (const v2f*)W1; const v2f* b1v = (const v2f*)b1;
  v2f h1[10];
#pragma unroll
  for (int j = 0; j < 10; j++) h1[j] = b1v[j];
#pragma unroll
  for (int k = 0; k < 10; k++) {
    float a = xi[k]; v2f av = {a, a};
#pragma unroll
    for (int j = 0; j < 10; j++) h1[j] += av * W1v[k*10 + j];
  }
  v2f out[10];
  mlp23_ln1(W2, b2, W3, b3, gw, bw, h1, out);
  store20v(xs + (size_t)i * 20, out);
}

// Per-layer node kernel, 1 node/thread, pk-fp32 — round-0 body, single packed
// weight pointer. NodeModel weights stream via s_load (SGPR operands); gp blob
// staged per-block into LDS (broadcast ds_read_b128, conflict-free).
// amdgpu_num_sgpr(96): SGPR alloc granule is 16; waves/SIMD = floor(800/alloc)
// needs alloc<=96 for 8 -> whole 1954-block grid resident in ONE generation
// (round-5 post-mortem: natural codegen settles at the 7-wave cliff, SGPR=112,
// leaving a 162-block straggler generation that doubles the wall). SGPR-only
// cap: pressure resolves via shallower s_load batching or v_writelane spills
// (VGPR 36->64 headroom) — NOT scratch (round-3/4's launch_bounds crushed
// VGPR too and spilled to scratch; this avoids that).
// Aggregation: deterministic DPP scan + run-end slot stores (no atomics).
__global__ __launch_bounds__(256) __attribute__((amdgpu_num_sgpr(96)))
void k_node(
    const int* __restrict__ batch, float* __restrict__ xs,
    float* __restrict__ ws, const float* __restrict__ wl, int n) {
  float* part = ws;                         // NG*80
  const float* gu = ws + NG * 80;           // NG*40
  __shared__ float sm[1280];
  int tid = threadIdx.x;
  stage4(sm, wl + 1280, 320, tid, 256);     // whole gp blob, contiguous
  __syncthreads();

  int i = blockIdx.x * 256 + tid;
  int lane = tid & 63;
  bool valid = i < n;
  int ic = valid ? i : (n - 1);
  int b = batch[ic];

  v2f x[10];
  load20v(xs + (size_t)ic * 20, x);

  // ---- NodeModel: h1 = x@W1x + gu_nm[b]  (gu = u@W1u + b1, prefolded) ----
  v2f h1[10];
  load20v(gu + (size_t)b * 40, h1);
  const v2f* W1v = (const v2f*)wl;
#pragma unroll
  for (int k = 0; k < 20; k++) {
    float a = elem(x, k); v2f av = {a, a};
#pragma unroll
    for (int j = 0; j < 10; j++) h1[j] += av * W1v[k*10 + j];
  }
  v2f xn[10];
  mlp23_ln1(wl + 400, wl + 1200, wl + 800, wl + 1220, wl + 1240, wl + 1260,
            h1, xn);
#pragma unroll
  for (int j = 0; j < 10; j++) xn[j] += x[j];     // residual
  if (valid) store20v(xs + (size_t)ic * 20, xn);

  // ---- pre-aggr MLP on updated x (weights from LDS broadcast) ----
  v2f p1[10];
  load20v(gu + (size_t)b * 40 + 20, p1);
  const v2f* G1v = (const v2f*)sm;
#pragma unroll
  for (int k = 0; k < 20; k++) {
    float a = elem(xn, k); v2f av = {a, a};
#pragma unroll
    for (int j = 0; j < 10; j++) p1[j] += av * G1v[k*10 + j];
  }
  v2f pre[10];
  mlp23_ln1(sm + 400, sm + 1200, sm + 800, sm + 1220, sm + 1240, sm + 1260,
            p1, pre);

  // ---- aggregation: DPP scan + run-end slot stores (batch sorted) ----
  int key = valid ? b : -1;
  if (!valid) {
#pragma unroll
    for (int j = 0; j < 10; j++) pre[j] = (v2f){0.0f, 0.0f};
  }
  int pk = __builtin_amdgcn_update_dpp(-1, key, 0x138, 0xF, 0xF, false);
  int nk = __builtin_amdgcn_update_dpp(-2, key, 0x130, 0xF, 0xF, false);
  bool isstart = (key != pk);
  int st = wscan_max(isstart ? lane : 0);   // start lane of my run

#pragma unroll
  for (int j = 0; j < 10; j++) {
    pre[j].x = wscan_add(pre[j].x);
    pre[j].y = wscan_add(pre[j].y);
  }

  int pl = (st > 0) ? (st - 1) : 0;
  float use = (st > 0) ? 1.0f : 0.0f;
  v2f fl[10];
#pragma unroll
  for (int j = 0; j < 10; j++) {
    float bx = __shfl(pre[j].x, pl);
    float by = __shfl(pre[j].y, pl);
    fl[j].x = pre[j].x - use * bx;
    fl[j].y = pre[j].y - use * by;
  }
  bool runend = valid && (nk != key);       // lane63 gets nk=-2 -> true
  if (runend) {
    int slot = (i >> 6) & 3;                // graphs span <=4 consecutive waves
    float* pp = part + (size_t)b * 80 + slot * 20;
#pragma unroll
    for (int j = 0; j < 10; j++) {
      pp[2*j]     = fl[j].x;
      pp[2*j + 1] = fl[j].y;
    }
  }
}

// Per-layer global kernel, 4 LANES PER GRAPH (NG*4 threads): coalesced slot
// loads, fixed-tree shfl butterflies, transposed weights in LDS. No slot
// re-zero needed — batch is constant across layers, so exactly the same
// (graph, slot) pairs are rewritten every layer; slots never written stay
// at their k_prelayer zeros.
__global__ __launch_bounds__(128) void k_global(
    float* __restrict__ u, float* __restrict__ part, float* __restrict__ gu,
    const float* __restrict__ qW1, const float* __restrict__ qb1,
    const float* __restrict__ qW2, const float* __restrict__ qb2,
    const float* __restrict__ qW3, const float* __restrict__ qb3,
    const float* __restrict__ qg,  const float* __restrict__ qbe,
    const float* __restrict__ nmW1u, const float* __restrict__ nmb1n,
    const float* __restrict__ gpW1u, const float* __restrict__ gpb1n,
    int has_next) {
  __shared__ float sW1T[20 * 40];   // [j][k], k over (agg | u)
  __shared__ float sW2T[20 * 20];   // [j][k]
  __shared__ float sW3T[20 * 20];
  __shared__ float sNT[20 * 20];    // nmW1u^T (next layer)
  __shared__ float sGT[20 * 20];    // gpW1u^T (next layer)
  __shared__ float sB[140];         // qb1|qb2|qb3|qg|qbe|nmb1n|gpb1n
  int tid = threadIdx.x;
  for (int e = tid; e < 800; e += 128) sW1T[(e % 20) * 40 + (e / 20)] = qW1[e];
  for (int e = tid; e < 400; e += 128) {
    int k = e / 20, j = e % 20;
    sW2T[j * 20 + k] = qW2[e];
    sW3T[j * 20 + k] = qW3[e];
    sNT[j * 20 + k]  = nmW1u[e];
    sGT[j * 20 + k]  = gpW1u[e];
  }
  if (tid < 20) {
    sB[tid]       = qb1[tid];
    sB[20 + tid]  = qb2[tid];
    sB[40 + tid]  = qb3[tid];
    sB[60 + tid]  = qg[tid];
    sB[80 + tid]  = qbe[tid];
    sB[100 + tid] = nmb1n[tid];
    sB[120 + tid] = gpb1n[tid];
  }
  __syncthreads();

  int t = blockIdx.x * 128 + tid;   // exactly NG*4 threads
  int g = t >> 2;                   // graph
  int q = t & 3;                    // quarter: output cols [q*5, q*5+5)
  int lane = tid & 63;
  int gl = lane & ~3;               // group base lane (groups never cross waves)

  // my partial slot (coalesced 80B/lane), then fixed-tree butterfly sum
  float a[20];
  {
    const float4* p = (const float4*)(part + (size_t)g * 80 + q * 20);
#pragma unroll
    for (int i = 0; i < 5; i++) {
      float4 f = p[i];
      a[4*i] = f.x; a[4*i+1] = f.y; a[4*i+2] = f.z; a[4*i+3] = f.w;
    }
  }
#pragma unroll
  for (int i = 0; i < 20; i++) {
    a[i] += __shfl_xor(a[i], 1);
    a[i] += __shfl_xor(a[i], 2);    // (s0+s1)+(s2+s3), same on all 4 lanes
  }

  float uu[20];
  {
    const float4* p = (const float4*)(u + (size_t)g * 20);
#pragma unroll
    for (int i = 0; i < 5; i++) {
      float4 f = p[i];
      uu[4*i] = f.x; uu[4*i+1] = f.y; uu[4*i+2] = f.z; uu[4*i+3] = f.w;
    }
  }

  // h1 slice: j = q*5+o ; h1_j = qb1[j] + a.W1[:,j](rows 0..19) + uu.W1[:,j](rows 20..39)
  float h1[5];
#pragma unroll
  for (int o = 0; o < 5; o++) {
    int j = q * 5 + o;
    const v2f* w = (const v2f*)(sW1T + j * 40);
    v2f acc = {0.0f, 0.0f};
#pragma unroll
    for (int kk = 0; kk < 10; kk++) acc += (v2f){a[2*kk], a[2*kk+1]} * w[kk];
#pragma unroll
    for (int kk = 0; kk < 10; kk++) acc += (v2f){uu[2*kk], uu[2*kk+1]} * w[10 + kk];
    h1[o] = sB[j] + acc.x + acc.y;
  }

  // gather relu(h1) across the 4-lane group (static unroll -> static reg idx)
  float r1[20];
#pragma unroll
  for (int k = 0; k < 20; k++)
    r1[k] = fmaxf(__shfl(h1[k % 5], gl + (k / 5)), 0.0f);

  float h2[5];
#pragma unroll
  for (int o = 0; o < 5; o++) {
    int j = q * 5 + o;
    const v2f* w = (const v2f*)(sW2T + j * 20);
    v2f acc = {0.0f, 0.0f};
#pragma unroll
    for (int kk = 0; kk < 10; kk++) acc += (v2f){r1[2*kk], r1[2*kk+1]} * w[kk];
    h2[o] = sB[20 + j] + acc.x + acc.y;
  }

  float r2[20];
#pragma unroll
  for (int k = 0; k < 20; k++)
    r2[k] = fmaxf(__shfl(h2[k % 5], gl + (k / 5)), 0.0f);

  float h3[5];
#pragma unroll
  for (int o = 0; o < 5; o++) {
    int j = q * 5 + o;
    const v2f* w = (const v2f*)(sW3T + j * 20);
    v2f acc = {0.0f, 0.0f};
#pragma unroll
    for (int kk = 0; kk < 10; kk++) acc += (v2f){r2[2*kk], r2[2*kk+1]} * w[kk];
    h3[o] = sB[40 + j] + acc.x + acc.y;
  }

  // group LayerNorm (fixed-tree butterflies)
  float s = h3[0] + h3[1] + h3[2] + h3[3] + h3[4];
  s += __shfl_xor(s, 1);
  s += __shfl_xor(s, 2);
  float mu = s * 0.05f;
  float d = 0.0f;
#pragma unroll
  for (int o = 0; o < 5; o++) { float dd = h3[o] - mu; d += dd * dd; }
  d += __shfl_xor(d, 1);
  d += __shfl_xor(d, 2);
  float rs = rsqrtf(d * 0.05f + LN_EPS);

  float un[5];
#pragma unroll
  for (int o = 0; o < 5; o++) {
    int j = q * 5 + o;
    un[o] = (h3[o] - mu) * rs * sB[60 + j] + sB[80 + j] + uu[j];  // +residual
  }
#pragma unroll
  for (int o = 0; o < 5; o++) u[(size_t)g * 20 + q * 5 + o] = un[o];

  if (has_next) {
    float ru[20];
#pragma unroll
    for (int k = 0; k < 20; k++)
      ru[k] = __shfl(un[k % 5], gl + (k / 5));
    float gn[5], gg[5];
#pragma unroll
    for (int o = 0; o < 5; o++) {
      int j = q * 5 + o;
      const v2f* wn = (const v2f*)(sNT + j * 20);
      const v2f* wg = (const v2f*)(sGT + j * 20);
      v2f an = {0.0f, 0.0f}, ag = {0.0f, 0.0f};
#pragma unroll
      for (int kk = 0; kk < 10; kk++) {
        v2f rv = {ru[2*kk], ru[2*kk+1]};
        an += rv * wn[kk];
        ag += rv * wg[kk];
      }
      gn[o] = sB[100 + j] + an.x + an.y;
      gg[o] = sB[120 + j] + ag.x + ag.y;
    }
#pragma unroll
    for (int o = 0; o < 5; o++) {
      gu[(size_t)g * 40 + q * 5 + o]      = gn[o];
      gu[(size_t)g * 40 + 20 + q * 5 + o] = gg[o];
    }
  }
}

// ---------------- host launcher ----------------

extern "C" void kernel_launch(void* const* d_in, const int* in_sizes, int n_in,
                              void* d_out, int out_size, void* d_ws, size_t ws_size,
                              hipStream_t stream) {
  const float* x_in  = (const float*)d_in[0];
  const int*   batch = (const int*)  d_in[1];
  const float* ni_W1 = (const float*)d_in[2];
  const float* ni_b1 = (const float*)d_in[3];
  const float* ni_W2 = (const float*)d_in[4];
  const float* ni_b2 = (const float*)d_in[5];
  const float* ni_W3 = (const float*)d_in[6];
  const float* ni_b3 = (const float*)d_in[7];
  const float* ni_g  = (const float*)d_in[8];
  const float* ni_be = (const float*)d_in[9];
  const float* nm_W1 = (const float*)d_in[10];
  const float* nm_b1 = (const float*)d_in[11];
  const float* nm_W2 = (const float*)d_in[12];
  const float* nm_b2 = (const float*)d_in[13];
  const float* nm_W3 = (const float*)d_in[14];
  const float* nm_b3 = (const float*)d_in[15];
  const float* nm_g  = (const float*)d_in[16];
  const float* nm_be = (const float*)d_in[17];
  const float* gp_W1 = (const float*)d_in[18];
  const float* gp_b1 = (const float*)d_in[19];
  const float* gp_W2 = (const float*)d_in[20];
  const float* gp_b2 = (const float*)d_in[21];
  const float* gp_W3 = (const float*)d_in[22];
  const float* gp_b3 = (const float*)d_in[23];
  const float* gp_g  = (const float*)d_in[24];
  const float* gp_be = (const float*)d_in[25];
  const float* gq_W1 = (const float*)d_in[26];
  const float* gq_b1 = (const float*)d_in[27];
  const float* gq_W2 = (const float*)d_in[28];
  const float* gq_b2 = (const float*)d_in[29];
  const float* gq_W3 = (const float*)d_in[30];
  const float* gq_b3 = (const float*)d_in[31];
  const float* gq_g  = (const float*)d_in[32];
  const float* gq_be = (const float*)d_in[33];

  const int N = in_sizes[0] / 10;          // 500000
  float* xs = (float*)d_out;               // x state in d_out[0 .. N*20)
  float* u  = xs + (size_t)N * 20;         // u in d_out tail (NG*20)

  float* part  = (float*)d_ws;             // NG*80 (4 slots x 20 per graph)
  float* gu    = part + NG * 80;           // NG*40 (merged nm|gp table)
  float* wpack = gu + NG * 40;             // L*2560 packed k_node weights

  const int L = 20;
  const int nblk = (N + 255) / 256;

  k_prelayer<<<(NG * 80) / 256, 256, 0, stream>>>(u, part, gu, nm_b1, gp_b1);
  k_pack<<<(L * 2560 + 255) / 256, 256, 0, stream>>>(wpack,
      nm_W1, nm_W2, nm_W3, nm_b2, nm_b3, nm_g, nm_be,
      gp_W1, gp_W2, gp_W3, gp_b2, gp_b3, gp_g, gp_be);
  k_init<<<nblk, 256, 0, stream>>>(x_in, xs, ni_W1, ni_b1, ni_W2, ni_b2,
                                   ni_W3, ni_b3, ni_g, ni_be, N);
  for (int l = 0; l < L; l++) {
    k_node<<<nblk, 256, 0, stream>>>(batch, xs, (float*)d_ws,
                                     wpack + (size_t)l * 2560, N);
    int has_next = (l < L - 1);
    k_global<<<(NG * 4) / 128, 128, 0, stream>>>(u, part, gu,
        gq_W1 + (size_t)l * 800, gq_b1 + l * 20,
        gq_W2 + (size_t)l * 400, gq_b2 + l * 20,
        gq_W3 + (size_t)l * 400, gq_b3 + l * 20,
        gq_g + l * 20, gq_be + l * 20,
        nm_W1 + (size_t)(l + 1) * 800 + 400, nm_b1 + (l + 1) * 20,
        gp_W1 + (size_t)(l + 1) * 800 + 400, gp_b1 + (l + 1) * 20,
        has_next);
  }
}

// Round 8
// 1255.423 us; speedup vs baseline: 1.2085x; 1.0412x over previous
//
#include <hip/hip_runtime.h>

#define NG 8192
#define LN_EPS 1e-5f

typedef float v2f __attribute__((ext_vector_type(2)));

// ---------------- DPP wave-scan helpers (VALU-only, no LDS pipe) ----------------

__device__ __forceinline__ float wscan_add(float x) {
  x += __int_as_float(__builtin_amdgcn_update_dpp(0, __float_as_int(x), 0x111, 0xF, 0xF, true));
  x += __int_as_float(__builtin_amdgcn_update_dpp(0, __float_as_int(x), 0x112, 0xF, 0xF, true));
  x += __int_as_float(__builtin_amdgcn_update_dpp(0, __float_as_int(x), 0x114, 0xF, 0xF, true));
  x += __int_as_float(__builtin_amdgcn_update_dpp(0, __float_as_int(x), 0x118, 0xF, 0xF, true));
  x += __int_as_float(__builtin_amdgcn_update_dpp(0, __float_as_int(x), 0x142, 0xA, 0xF, false));
  x += __int_as_float(__builtin_amdgcn_update_dpp(0, __float_as_int(x), 0x143, 0xC, 0xF, false));
  return x;
}

__device__ __forceinline__ int wscan_max(int x) {
  int t;
  t = __builtin_amdgcn_update_dpp(0, x, 0x111, 0xF, 0xF, true); x = max(x, t);
  t = __builtin_amdgcn_update_dpp(0, x, 0x112, 0xF, 0xF, true); x = max(x, t);
  t = __builtin_amdgcn_update_dpp(0, x, 0x114, 0xF, 0xF, true); x = max(x, t);
  t = __builtin_amdgcn_update_dpp(0, x, 0x118, 0xF, 0xF, true); x = max(x, t);
  t = __builtin_amdgcn_update_dpp(0, x, 0x142, 0xA, 0xF, false); x = max(x, t);
  t = __builtin_amdgcn_update_dpp(0, x, 0x143, 0xC, 0xF, false); x = max(x, t);
  return x;
}

// ---------------- misc helpers ----------------

__device__ __forceinline__ void stage4(float* dst, const float* __restrict__ src,
                                       int n4, int tid, int nt) {
  float4* d = (float4*)dst;
  const float4* s = (const float4*)src;
  for (int t = tid; t < n4; t += nt) d[t] = s[t];
}

__device__ __forceinline__ void load20v(const float* __restrict__ p, v2f v[10]) {
  const float4* q = (const float4*)p;
#pragma unroll
  for (int t = 0; t < 5; t++) {
    float4 f = q[t];
    v[2*t]   = (v2f){f.x, f.y};
    v[2*t+1] = (v2f){f.z, f.w};
  }
}

__device__ __forceinline__ void store20v(float* __restrict__ p, const v2f v[10]) {
  float4* q = (float4*)p;
#pragma unroll
  for (int t = 0; t < 5; t++)
    q[t] = make_float4(v[2*t].x, v[2*t].y, v[2*t+1].x, v[2*t+1].y);
}

__device__ __forceinline__ float elem(const v2f* a, int k) { return a[k >> 1][k & 1]; }

// LN(relu(relu(h1)@W2+b2)@W3+b3)*g+be — packed fp32 pairs. Works for both
// global (SGPR s_load) and LDS (broadcast ds_read) weight pointers (inlined).
__device__ __forceinline__ void mlp23_ln1(
    const float* __restrict__ W2, const float* __restrict__ b2,
    const float* __restrict__ W3, const float* __restrict__ b3,
    const float* __restrict__ g,  const float* __restrict__ be,
    const v2f h1[10], v2f out[10]) {
  const v2f* W2v = (const v2f*)W2; const v2f* b2v = (const v2f*)b2;
  const v2f* W3v = (const v2f*)W3; const v2f* b3v = (const v2f*)b3;
  const v2f* gv  = (const v2f*)g;  const v2f* bev = (const v2f*)be;
  v2f h2[10];
#pragma unroll
  for (int j = 0; j < 10; j++) h2[j] = b2v[j];
#pragma unroll
  for (int k = 0; k < 20; k++) {
    float a = fmaxf(elem(h1, k), 0.0f); v2f av = {a, a};
#pragma unroll
    for (int j = 0; j < 10; j++) h2[j] += av * W2v[k*10 + j];
  }
  v2f h3[10];
#pragma unroll
  for (int j = 0; j < 10; j++) h3[j] = b3v[j];
#pragma unroll
  for (int k = 0; k < 20; k++) {
    float a = fmaxf(elem(h2, k), 0.0f); v2f av = {a, a};
#pragma unroll
    for (int j = 0; j < 10; j++) h3[j] += av * W3v[k*10 + j];
  }
  float mu = 0.0f;
#pragma unroll
  for (int j = 0; j < 10; j++) mu += h3[j].x + h3[j].y;
  mu *= 0.05f;
  float var = 0.0f;
#pragma unroll
  for (int j = 0; j < 10; j++) {
    float dx = h3[j].x - mu, dy = h3[j].y - mu;
    var += dx*dx + dy*dy;
  }
  var *= 0.05f;
  float rs = rsqrtf(var + LN_EPS);
  v2f muv = {mu, mu}, rsv = {rs, rs};
#pragma unroll
  for (int j = 0; j < 10; j++) out[j] = (h3[j] - muv) * rsv * gv[j] + bev[j];
}

// ---------------- kernels ----------------

__global__ __launch_bounds__(256) void k_prelayer(
    float* __restrict__ u, float* __restrict__ part, float* __restrict__ gu,
    const float* __restrict__ nmb1, const float* __restrict__ gpb1) {
  int t = blockIdx.x * 256 + threadIdx.x;   // NG*80 threads
  part[t] = 0.0f;
  if (t < NG * 40) {
    int j = t % 40;
    gu[t] = (j < 20) ? nmb1[j] : gpb1[j - 20];
  }
  if (t < NG * 20) u[t] = 0.0f;
}

// One-time weight packer: per layer l, blob of 2560 floats =
// [nmW1x 400][nmW2 400][nmW3 400][nmb2 20][nmb3 20][nmg 20][nmbe 20] (=1280)
// [gpW1x 400][gpW2 400][gpW3 400][gpb2 20][gpb3 20][gpg 20][gpbe 20] (=1280)
__global__ __launch_bounds__(256) void k_pack(
    float* __restrict__ wp,
    const float* __restrict__ nmW1, const float* __restrict__ nmW2,
    const float* __restrict__ nmW3, const float* __restrict__ nmb2,
    const float* __restrict__ nmb3, const float* __restrict__ nmg,
    const float* __restrict__ nmbe,
    const float* __restrict__ gpW1, const float* __restrict__ gpW2,
    const float* __restrict__ gpW3, const float* __restrict__ gpb2,
    const float* __restrict__ gpb3, const float* __restrict__ gpg,
    const float* __restrict__ gpbe) {
  int t = blockIdx.x * 256 + threadIdx.x;
  if (t >= 20 * 2560) return;
  int l = t / 2560, r = t % 2560;
  int half = (r >= 1280) ? 1 : 0;
  int rr = r - half * 1280;
  float v;
  if (rr < 400)       v = (half ? gpW1 : nmW1)[l * 800 + rr];       // x-rows only
  else if (rr < 800)  v = (half ? gpW2 : nmW2)[l * 400 + rr - 400];
  else if (rr < 1200) v = (half ? gpW3 : nmW3)[l * 400 + rr - 800];
  else if (rr < 1220) v = (half ? gpb2 : nmb2)[l * 20 + rr - 1200];
  else if (rr < 1240) v = (half ? gpb3 : nmb3)[l * 20 + rr - 1220];
  else if (rr < 1260) v = (half ? gpg  : nmg )[l * 20 + rr - 1240];
  else                v = (half ? gpbe : nmbe)[l * 20 + rr - 1260];
  wp[t] = v;
}

__global__ __launch_bounds__(256) void k_init(
    const float* __restrict__ xin, float* __restrict__ xs,
    const float* __restrict__ W1, const float* __restrict__ b1,
    const float* __restrict__ W2, const float* __restrict__ b2,
    const float* __restrict__ W3, const float* __restrict__ b3,
    const float* __restrict__ gw, const float* __restrict__ bw, int n) {
  int i = blockIdx.x * 256 + threadIdx.x;
  if (i >= n) return;
  float xi[10];
  const float2* xp = (const float2*)(xin + (size_t)i * 10);
#pragma unroll
  for (int t = 0; t < 5; t++) { float2 f = xp[t]; xi[t*2] = f.x; xi[t*2+1] = f.y; }
  const v2f* W1v = (const v2f*)W1; const v2f* b1v = (const v2f*)b1;
  v2f h1[10];
#pragma unroll
  for (int j = 0; j < 10; j++) h1[j] = b1v[j];
#pragma unroll
  for (int k = 0; k < 10; k++) {
    float a = xi[k]; v2f av = {a, a};
#pragma unroll
    for (int j = 0; j < 10; j++) h1[j] += av * W1v[k*10 + j];
  }
  v2f out[10];
  mlp23_ln1(W2, b2, W3, b3, gw, bw, h1, out);
  store20v(xs + (size_t)i * 20, out);
}

// Per-layer node kernel, 1 node/thread, pk-fp32 — round-0 body, single packed
// weight pointer. NodeModel weights stream via s_load (SGPR operands); gp blob
// staged per-block into LDS (broadcast ds_read_b128, conflict-free).
// amdgpu_num_sgpr(80): round-6 showed reported SGPR=96 still gives only 7
// waves/SIMD — the HW adds ~16 hidden SGPRs (vcc/flat-scratch/xnack +
// trap-handler reservation) on top of the reported count: 96+16=112 ->
// 800/112=7. Requesting 80 makes the per-wave total <=96 -> 800/96=8.33 ->
// 8 waves/SIMD -> capacity 2048 >= 1954-block grid -> SINGLE generation
// (the straggler generation at 0.6 blocks/CU is the measured 2x wall).
// Safe under all hidden-size hypotheses (hidden=0 -> 10 waves, capped at 8
// by the 2048-thread/CU limit). SGPR pressure resolves via writelane spills
// to VGPR (36->64 headroom), not scratch (round-6 verified graceful).
// [Round 7 was an infra failure (container acquire), not a kernel result —
// this is a clean re-run of the same experiment.]
// Aggregation: deterministic DPP scan + run-end slot stores (no atomics).
__global__ __launch_bounds__(256) __attribute__((amdgpu_num_sgpr(80)))
void k_node(
    const int* __restrict__ batch, float* __restrict__ xs,
    float* __restrict__ ws, const float* __restrict__ wl, int n) {
  float* part = ws;                         // NG*80
  const float* gu = ws + NG * 80;           // NG*40
  __shared__ float sm[1280];
  int tid = threadIdx.x;
  stage4(sm, wl + 1280, 320, tid, 256);     // whole gp blob, contiguous
  __syncthreads();

  int i = blockIdx.x * 256 + tid;
  int lane = tid & 63;
  bool valid = i < n;
  int ic = valid ? i : (n - 1);
  int b = batch[ic];

  v2f x[10];
  load20v(xs + (size_t)ic * 20, x);

  // ---- NodeModel: h1 = x@W1x + gu_nm[b]  (gu = u@W1u + b1, prefolded) ----
  v2f h1[10];
  load20v(gu + (size_t)b * 40, h1);
  const v2f* W1v = (const v2f*)wl;
#pragma unroll
  for (int k = 0; k < 20; k++) {
    float a = elem(x, k); v2f av = {a, a};
#pragma unroll
    for (int j = 0; j < 10; j++) h1[j] += av * W1v[k*10 + j];
  }
  v2f xn[10];
  mlp23_ln1(wl + 400, wl + 1200, wl + 800, wl + 1220, wl + 1240, wl + 1260,
            h1, xn);
#pragma unroll
  for (int j = 0; j < 10; j++) xn[j] += x[j];     // residual
  if (valid) store20v(xs + (size_t)ic * 20, xn);

  // ---- pre-aggr MLP on updated x (weights from LDS broadcast) ----
  v2f p1[10];
  load20v(gu + (size_t)b * 40 + 20, p1);
  const v2f* G1v = (const v2f*)sm;
#pragma unroll
  for (int k = 0; k < 20; k++) {
    float a = elem(xn, k); v2f av = {a, a};
#pragma unroll
    for (int j = 0; j < 10; j++) p1[j] += av * G1v[k*10 + j];
  }
  v2f pre[10];
  mlp23_ln1(sm + 400, sm + 1200, sm + 800, sm + 1220, sm + 1240, sm + 1260,
            p1, pre);

  // ---- aggregation: DPP scan + run-end slot stores (batch sorted) ----
  int key = valid ? b : -1;
  if (!valid) {
#pragma unroll
    for (int j = 0; j < 10; j++) pre[j] = (v2f){0.0f, 0.0f};
  }
  int pk = __builtin_amdgcn_update_dpp(-1, key, 0x138, 0xF, 0xF, false);
  int nk = __builtin_amdgcn_update_dpp(-2, key, 0x130, 0xF, 0xF, false);
  bool isstart = (key != pk);
  int st = wscan_max(isstart ? lane : 0);   // start lane of my run

#pragma unroll
  for (int j = 0; j < 10; j++) {
    pre[j].x = wscan_add(pre[j].x);
    pre[j].y = wscan_add(pre[j].y);
  }

  int pl = (st > 0) ? (st - 1) : 0;
  float use = (st > 0) ? 1.0f : 0.0f;
  v2f fl[10];
#pragma unroll
  for (int j = 0; j < 10; j++) {
    float bx = __shfl(pre[j].x, pl);
    float by = __shfl(pre[j].y, pl);
    fl[j].x = pre[j].x - use * bx;
    fl[j].y = pre[j].y - use * by;
  }
  bool runend = valid && (nk != key);       // lane63 gets nk=-2 -> true
  if (runend) {
    int slot = (i >> 6) & 3;                // graphs span <=4 consecutive waves
    float* pp = part + (size_t)b * 80 + slot * 20;
#pragma unroll
    for (int j = 0; j < 10; j++) {
      pp[2*j]     = fl[j].x;
      pp[2*j + 1] = fl[j].y;
    }
  }
}

// Per-layer global kernel, 4 LANES PER GRAPH (NG*4 threads): coalesced slot
// loads, fixed-tree shfl butterflies, transposed weights in LDS. No slot
// re-zero needed — batch is constant across layers, so exactly the same
// (graph, slot) pairs are rewritten every layer; slots never written stay
// at their k_prelayer zeros.
__global__ __launch_bounds__(128) void k_global(
    float* __restrict__ u, float* __restrict__ part, float* __restrict__ gu,
    const float* __restrict__ qW1, const float* __restrict__ qb1,
    const float* __restrict__ qW2, const float* __restrict__ qb2,
    const float* __restrict__ qW3, const float* __restrict__ qb3,
    const float* __restrict__ qg,  const float* __restrict__ qbe,
    const float* __restrict__ nmW1u, const float* __restrict__ nmb1n,
    const float* __restrict__ gpW1u, const float* __restrict__ gpb1n,
    int has_next) {
  __shared__ float sW1T[20 * 40];   // [j][k], k over (agg | u)
  __shared__ float sW2T[20 * 20];   // [j][k]
  __shared__ float sW3T[20 * 20];
  __shared__ float sNT[20 * 20];    // nmW1u^T (next layer)
  __shared__ float sGT[20 * 20];    // gpW1u^T (next layer)
  __shared__ float sB[140];         // qb1|qb2|qb3|qg|qbe|nmb1n|gpb1n
  int tid = threadIdx.x;
  for (int e = tid; e < 800; e += 128) sW1T[(e % 20) * 40 + (e / 20)] = qW1[e];
  for (int e = tid; e < 400; e += 128) {
    int k = e / 20, j = e % 20;
    sW2T[j * 20 + k] = qW2[e];
    sW3T[j * 20 + k] = qW3[e];
    sNT[j * 20 + k]  = nmW1u[e];
    sGT[j * 20 + k]  = gpW1u[e];
  }
  if (tid < 20) {
    sB[tid]       = qb1[tid];
    sB[20 + tid]  = qb2[tid];
    sB[40 + tid]  = qb3[tid];
    sB[60 + tid]  = qg[tid];
    sB[80 + tid]  = qbe[tid];
    sB[100 + tid] = nmb1n[tid];
    sB[120 + tid] = gpb1n[tid];
  }
  __syncthreads();

  int t = blockIdx.x * 128 + tid;   // exactly NG*4 threads
  int g = t >> 2;                   // graph
  int q = t & 3;                    // quarter: output cols [q*5, q*5+5)
  int lane = tid & 63;
  int gl = lane & ~3;               // group base lane (groups never cross waves)

  // my partial slot (coalesced 80B/lane), then fixed-tree butterfly sum
  float a[20];
  {
    const float4* p = (const float4*)(part + (size_t)g * 80 + q * 20);
#pragma unroll
    for (int i = 0; i < 5; i++) {
      float4 f = p[i];
      a[4*i] = f.x; a[4*i+1] = f.y; a[4*i+2] = f.z; a[4*i+3] = f.w;
    }
  }
#pragma unroll
  for (int i = 0; i < 20; i++) {
    a[i] += __shfl_xor(a[i], 1);
    a[i] += __shfl_xor(a[i], 2);    // (s0+s1)+(s2+s3), same on all 4 lanes
  }

  float uu[20];
  {
    const float4* p = (const float4*)(u + (size_t)g * 20);
#pragma unroll
    for (int i = 0; i < 5; i++) {
      float4 f = p[i];
      uu[4*i] = f.x; uu[4*i+1] = f.y; uu[4*i+2] = f.z; uu[4*i+3] = f.w;
    }
  }

  // h1 slice: j = q*5+o ; h1_j = qb1[j] + a.W1[:,j](rows 0..19) + uu.W1[:,j](rows 20..39)
  float h1[5];
#pragma unroll
  for (int o = 0; o < 5; o++) {
    int j = q * 5 + o;
    const v2f* w = (const v2f*)(sW1T + j * 40);
    v2f acc = {0.0f, 0.0f};
#pragma unroll
    for (int kk = 0; kk < 10; kk++) acc += (v2f){a[2*kk], a[2*kk+1]} * w[kk];
#pragma unroll
    for (int kk = 0; kk < 10; kk++) acc += (v2f){uu[2*kk], uu[2*kk+1]} * w[10 + kk];
    h1[o] = sB[j] + acc.x + acc.y;
  }

  // gather relu(h1) across the 4-lane group (static unroll -> static reg idx)
  float r1[20];
#pragma unroll
  for (int k = 0; k < 20; k++)
    r1[k] = fmaxf(__shfl(h1[k % 5], gl + (k / 5)), 0.0f);

  float h2[5];
#pragma unroll
  for (int o = 0; o < 5; o++) {
    int j = q * 5 + o;
    const v2f* w = (const v2f*)(sW2T + j * 20);
    v2f acc = {0.0f, 0.0f};
#pragma unroll
    for (int kk = 0; kk < 10; kk++) acc += (v2f){r1[2*kk], r1[2*kk+1]} * w[kk];
    h2[o] = sB[20 + j] + acc.x + acc.y;
  }

  float r2[20];
#pragma unroll
  for (int k = 0; k < 20; k++)
    r2[k] = fmaxf(__shfl(h2[k % 5], gl + (k / 5)), 0.0f);

  float h3[5];
#pragma unroll
  for (int o = 0; o < 5; o++) {
    int j = q * 5 + o;
    const v2f* w = (const v2f*)(sW3T + j * 20);
    v2f acc = {0.0f, 0.0f};
#pragma unroll
    for (int kk = 0; kk < 10; kk++) acc += (v2f){r2[2*kk], r2[2*kk+1]} * w[kk];
    h3[o] = sB[40 + j] + acc.x + acc.y;
  }

  // group LayerNorm (fixed-tree butterflies)
  float s = h3[0] + h3[1] + h3[2] + h3[3] + h3[4];
  s += __shfl_xor(s, 1);
  s += __shfl_xor(s, 2);
  float mu = s * 0.05f;
  float d = 0.0f;
#pragma unroll
  for (int o = 0; o < 5; o++) { float dd = h3[o] - mu; d += dd * dd; }
  d += __shfl_xor(d, 1);
  d += __shfl_xor(d, 2);
  float rs = rsqrtf(d * 0.05f + LN_EPS);

  float un[5];
#pragma unroll
  for (int o = 0; o < 5; o++) {
    int j = q * 5 + o;
    un[o] = (h3[o] - mu) * rs * sB[60 + j] + sB[80 + j] + uu[j];  // +residual
  }
#pragma unroll
  for (int o = 0; o < 5; o++) u[(size_t)g * 20 + q * 5 + o] = un[o];

  if (has_next) {
    float ru[20];
#pragma unroll
    for (int k = 0; k < 20; k++)
      ru[k] = __shfl(un[k % 5], gl + (k / 5));
    float gn[5], gg[5];
#pragma unroll
    for (int o = 0; o < 5; o++) {
      int j = q * 5 + o;
      const v2f* wn = (const v2f*)(sNT + j * 20);
      const v2f* wg = (const v2f*)(sGT + j * 20);
      v2f an = {0.0f, 0.0f}, ag = {0.0f, 0.0f};
#pragma unroll
      for (int kk = 0; kk < 10; kk++) {
        v2f rv = {ru[2*kk], ru[2*kk+1]};
        an += rv * wn[kk];
        ag += rv * wg[kk];
      }
      gn[o] = sB[100 + j] + an.x + an.y;
      gg[o] = sB[120 + j] + ag.x + ag.y;
    }
#pragma unroll
    for (int o = 0; o < 5; o++) {
      gu[(size_t)g * 40 + q * 5 + o]      = gn[o];
      gu[(size_t)g * 40 + 20 + q * 5 + o] = gg[o];
    }
  }
}

// ---------------- host launcher ----------------

extern "C" void kernel_launch(void* const* d_in, const int* in_sizes, int n_in,
                              void* d_out, int out_size, void* d_ws, size_t ws_size,
                              hipStream_t stream) {
  const float* x_in  = (const float*)d_in[0];
  const int*   batch = (const int*)  d_in[1];
  const float* ni_W1 = (const float*)d_in[2];
  const float* ni_b1 = (const float*)d_in[3];
  const float* ni_W2 = (const float*)d_in[4];
  const float* ni_b2 = (const float*)d_in[5];
  const float* ni_W3 = (const float*)d_in[6];
  const float* ni_b3 = (const float*)d_in[7];
  const float* ni_g  = (const float*)d_in[8];
  const float* ni_be = (const float*)d_in[9];
  const float* nm_W1 = (const float*)d_in[10];
  const float* nm_b1 = (const float*)d_in[11];
  const float* nm_W2 = (const float*)d_in[12];
  const float* nm_b2 = (const float*)d_in[13];
  const float* nm_W3 = (const float*)d_in[14];
  const float* nm_b3 = (const float*)d_in[15];
  const float* nm_g  = (const float*)d_in[16];
  const float* nm_be = (const float*)d_in[17];
  const float* gp_W1 = (const float*)d_in[18];
  const float* gp_b1 = (const float*)d_in[19];
  const float* gp_W2 = (const float*)d_in[20];
  const float* gp_b2 = (const float*)d_in[21];
  const float* gp_W3 = (const float*)d_in[22];
  const float* gp_b3 = (const float*)d_in[23];
  const float* gp_g  = (const float*)d_in[24];
  const float* gp_be = (const float*)d_in[25];
  const float* gq_W1 = (const float*)d_in[26];
  const float* gq_b1 = (const float*)d_in[27];
  const float* gq_W2 = (const float*)d_in[28];
  const float* gq_b2 = (const float*)d_in[29];
  const float* gq_W3 = (const float*)d_in[30];
  const float* gq_b3 = (const float*)d_in[31];
  const float* gq_g  = (const float*)d_in[32];
  const float* gq_be = (const float*)d_in[33];

  const int N = in_sizes[0] / 10;          // 500000
  float* xs = (float*)d_out;               // x state in d_out[0 .. N*20)
  float* u  = xs + (size_t)N * 20;         // u in d_out tail (NG*20)

  float* part  = (float*)d_ws;             // NG*80 (4 slots x 20 per graph)
  float* gu    = part + NG * 80;           // NG*40 (merged nm|gp table)
  float* wpack = gu + NG * 40;             // L*2560 packed k_node weights

  const int L = 20;
  const int nblk = (N + 255) / 256;

  k_prelayer<<<(NG * 80) / 256, 256, 0, stream>>>(u, part, gu, nm_b1, gp_b1);
  k_pack<<<(L * 2560 + 255) / 256, 256, 0, stream>>>(wpack,
      nm_W1, nm_W2, nm_W3, nm_b2, nm_b3, nm_g, nm_be,
      gp_W1, gp_W2, gp_W3, gp_b2, gp_b3, gp_g, gp_be);
  k_init<<<nblk, 256, 0, stream>>>(x_in, xs, ni_W1, ni_b1, ni_W2, ni_b2,
                                   ni_W3, ni_b3, ni_g, ni_be, N);
  for (int l = 0; l < L; l++) {
    k_node<<<nblk, 256, 0, stream>>>(batch, xs, (float*)d_ws,
                                     wpack + (size_t)l * 2560, N);
    int has_next = (l < L - 1);
    k_global<<<(NG * 4) / 128, 128, 0, stream>>>(u, part, gu,
        gq_W1 + (size_t)l * 800, gq_b1 + l * 20,
        gq_W2 + (size_t)l * 400, gq_b2 + l * 20,
        gq_W3 + (size_t)l * 400, gq_b3 + l * 20,
        gq_g + l * 20, gq_be + l * 20,
        nm_W1 + (size_t)(l + 1) * 800 + 400, nm_b1 + (l + 1) * 20,
        gp_W1 + (size_t)(l + 1) * 800 + 400, gp_b1 + (l + 1) * 20,
        has_next);
  }
}